// Round 1
// 694.060 us; speedup vs baseline: 1.1361x; 1.1361x over previous
//
#include <hip/hip_runtime.h>
#include <hip/hip_bf16.h>
#include <stdint.h>

#define EPSV 1e-5f
#define BKLG 10
#define BK 1024
#define P1CHUNK 16384

// ---------------- init ----------------

// zero bucket counts (256) and BN stats (64) -- single block
__global__ void k_zero(int* __restrict__ bcnt, float* __restrict__ stats) {
  int t = threadIdx.x;
  bcnt[t] = 0;
  if (t < 64) stats[t] = 0.f;
}

// ---------------- graph build ----------------
// Structure: bucket = 1024 consecutive dst nodes (NB <= 256 buckets).
// 1) k_bcount: per-bucket edge counts (LDS-aggregated histogram).
// 2) k_bscan:  exclusive scan of bucket counts -> bucket base offsets
//              (ticket = staging cursors, bbeg = stable copy), offs[N]=E.
// 3) k_bin:    bin edges into per-bucket staging streams (packed src|dstLocal).
// 4) k_place:  per bucket: LDS histogram of local dst -> in-block scan gives
//              per-node offs/dinv AND placement cursors; scatter src into CSR.
// This removes the global per-node atomicAdd degree pass entirely (was ~100MB
// of 32B atomic write transactions = the largest dispatch).

// per-bucket counts via LDS histogram; requires NB <= 256
__global__ __launch_bounds__(256) void k_bcount(const int* __restrict__ e32, int E, int NB,
                                                int* __restrict__ bcnt) {
  __shared__ int cnt[256];
  int t = threadIdx.x;
  cnt[t] = 0;
  __syncthreads();
  int e0 = blockIdx.x * P1CHUNK;
  int e1 = min(e0 + P1CHUNK, E);
  for (int i = e0 + t; i < e1; i += 256) {
    int d = e32[(size_t)E + i];
    atomicAdd(&cnt[d >> BKLG], 1);
  }
  __syncthreads();
  if (t < NB) {
    int c = cnt[t];
    if (c) atomicAdd(&bcnt[t], c);
  }
}

// exclusive scan of bcnt[NB] (NB<=256), single block; also offs[N]=E
__global__ void k_bscan(const int* __restrict__ bcnt, int NB, int E, int N,
                        int* __restrict__ ticket, int* __restrict__ bbeg,
                        int* __restrict__ offs) {
  __shared__ int sd[256];
  int t = threadIdx.x;
  int v = (t < NB) ? bcnt[t] : 0;
  sd[t] = v;
  __syncthreads();
  for (int st = 1; st < 256; st <<= 1) {
    int add = (t >= st) ? sd[t - st] : 0;
    __syncthreads();
    sd[t] += add;
    __syncthreads();
  }
  int ex = sd[t] - v;
  if (t < NB) {
    ticket[t] = ex;
    bbeg[t] = ex;
  }
  if (t == 0) {
    bbeg[NB] = E;
    offs[N] = E;
  }
}

// phase 1: bin edges into per-bucket staging streams (packed src|dstLocal)
// requires N <= 2^18 (src packs in 18 bits) and NB <= 256
__global__ __launch_bounds__(256) void k_bin(const int* __restrict__ e32, int E, int NB,
                                             int* __restrict__ ticket,
                                             unsigned* __restrict__ staged) {
  __shared__ int cnt[256];
  __shared__ int base[256];
  int t = threadIdx.x;
  int e0 = blockIdx.x * P1CHUNK;
  int e1 = min(e0 + P1CHUNK, E);
  if (t < NB) cnt[t] = 0;
  __syncthreads();
  for (int i = e0 + t; i < e1; i += 256) {
    int d = e32[(size_t)E + i];
    atomicAdd(&cnt[d >> BKLG], 1);
  }
  __syncthreads();
  if (t < NB) {
    int c = cnt[t];
    base[t] = c ? atomicAdd(&ticket[t], c) : 0;
    cnt[t] = 0;
  }
  __syncthreads();
  for (int i = e0 + t; i < e1; i += 256) {
    int s = e32[i];
    int d = e32[(size_t)E + i];
    int b = d >> BKLG;
    int l = atomicAdd(&cnt[b], 1);
    staged[base[b] + l] = (unsigned)s | ((unsigned)(d & (BK - 1)) << 18);
  }
}

// phase 2: one workgroup per bucket.
// Pass A: LDS histogram of local dst over staged edges (L2-resident re-read).
// In-block scan -> per-node CSR offsets (written to offs[]) + dinv[].
// Pass B: scatter src into contiguous CSR region via LDS cursors.
__global__ __launch_bounds__(256) void k_place(const unsigned* __restrict__ staged,
                                               const int* __restrict__ bbeg, int N,
                                               int* __restrict__ csr,
                                               int* __restrict__ offs,
                                               float* __restrict__ dinv) {
  __shared__ int hist[BK];
  __shared__ int lpos[BK];
  __shared__ int sd[256];
  int b = blockIdx.x;
  int n0 = b << BKLG;
  int t = threadIdx.x;
  for (int i = t; i < BK; i += 256) hist[i] = 0;
  __syncthreads();
  int beg = bbeg[b], endp = bbeg[b + 1];
  for (int j = beg + t; j < endp; j += 256) {
    unsigned v = staged[j];
    atomicAdd(&hist[v >> 18], 1);
  }
  __syncthreads();
  // exclusive scan of hist[0..1023]; thread t owns 4 consecutive entries
  int i0 = t * 4;
  int h0 = hist[i0], h1 = hist[i0 + 1], h2 = hist[i0 + 2], h3 = hist[i0 + 3];
  int s = h0 + h1 + h2 + h3;
  sd[t] = s;
  __syncthreads();
  for (int st = 1; st < 256; st <<= 1) {
    int add = (t >= st) ? sd[t - st] : 0;
    __syncthreads();
    sd[t] += add;
    __syncthreads();
  }
  int ex = sd[t] - s;  // exclusive across threads
  int l0 = ex, l1 = ex + h0, l2 = l1 + h1, l3 = l2 + h2;
  lpos[i0] = beg + l0;
  lpos[i0 + 1] = beg + l1;
  lpos[i0 + 2] = beg + l2;
  lpos[i0 + 3] = beg + l3;
  int node = n0 + i0;
  if (node < N) {
    offs[node] = beg + l0;
    dinv[node] = rsqrtf((float)(h0 + 1));
  }
  if (node + 1 < N) {
    offs[node + 1] = beg + l1;
    dinv[node + 1] = rsqrtf((float)(h1 + 1));
  }
  if (node + 2 < N) {
    offs[node + 2] = beg + l2;
    dinv[node + 2] = rsqrtf((float)(h2 + 1));
  }
  if (node + 3 < N) {
    offs[node + 3] = beg + l3;
    dinv[node + 3] = rsqrtf((float)(h3 + 1));
  }
  __syncthreads();
  for (int j = beg + t; j < endp; j += 256) {
    unsigned v = staged[j];
    int dl = (int)(v >> 18);
    int p = atomicAdd(&lpos[dl], 1);
    csr[p] = (int)(v & 0x3FFFFu);
  }
}

// ---------------- layer kernels ----------------

// hs[row] = (x[row] @ W) * dinv[row]   (x: N x 256, W: 256 x 16)
// barrier-free: one row per thread, float4 streaming loads, W via uniform s_loads
__global__ __launch_bounds__(256) void k_gemm1(const float* __restrict__ x,
                                               const float* __restrict__ W,
                                               const float* __restrict__ dinv, int N,
                                               float* __restrict__ hs) {
  int row = blockIdx.x * 256 + threadIdx.x;
  if (row >= N) return;
  const float4* xr = (const float4*)(x + (size_t)row * 256);
  float acc[16];
#pragma unroll
  for (int c = 0; c < 16; c++) acc[c] = 0.f;
#pragma unroll 8
  for (int j = 0; j < 64; j++) {
    float4 v = xr[j];
    const float* w0 = W + j * 64;  // W rows 4j..4j+3 (uniform -> s_load)
#pragma unroll
    for (int c = 0; c < 16; c++) {
      float t0 = fmaf(v.x, w0[c], acc[c]);
      float t1 = fmaf(v.y, w0[16 + c], t0);
      float t2 = fmaf(v.z, w0[32 + c], t1);
      acc[c] = fmaf(v.w, w0[48 + c], t2);
    }
  }
  float dv = dinv[row];
  float4* o4 = (float4*)(hs + (size_t)row * 16);
#pragma unroll
  for (int i = 0; i < 4; i++)
    o4[i] = make_float4(acc[i * 4] * dv, acc[i * 4 + 1] * dv, acc[i * 4 + 2] * dv,
                        acc[i * 4 + 3] * dv);
}

// out[d] = dinv[d]*(hs[d] + sum_{in-edges} hs[src]) + bias   -- 4 lanes per node
__global__ void k_agg(const float* __restrict__ hs, const int* __restrict__ csr,
                      const int* __restrict__ offs, const float* __restrict__ dinv,
                      const float* __restrict__ bias, int N, float* __restrict__ out) {
  int g = blockIdx.x * 256 + threadIdx.x;
  int node = g >> 2, q = g & 3;
  if (node >= N) return;
  int beg = offs[node], end = offs[node + 1];
  const float4* hs4 = (const float4*)hs;
  float4 a = hs4[(size_t)node * 4 + q];
  for (int j = beg; j < end; j++) {
    int s = csr[j];
    float4 v = hs4[(size_t)s * 4 + q];
    a.x += v.x; a.y += v.y; a.z += v.z; a.w += v.w;
  }
  float dv = dinv[node];
  float4 b = ((const float4*)bias)[q];
  ((float4*)out)[(size_t)node * 4 + q] =
      make_float4(fmaf(a.x, dv, b.x), fmaf(a.y, dv, b.y), fmaf(a.z, dv, b.z), fmaf(a.w, dv, b.w));
}

// per-channel sum / sumsq over rows
__global__ void k_bnstats(const float* __restrict__ o, int N, float* __restrict__ stats) {
  __shared__ float ss[256];
  __shared__ float sq[256];
  int t = threadIdx.x;
  int c = t & 15;
  int r = blockIdx.x * 16 + (t >> 4);
  int stride = gridDim.x * 16;
  float s = 0.f, q = 0.f;
  for (; r < N; r += stride) {
    float v = o[(size_t)r * 16 + c];
    s += v;
    q = fmaf(v, v, q);
  }
  ss[t] = s;
  sq[t] = q;
  __syncthreads();
  for (int st = 128; st >= 16; st >>= 1) {
    if (t < st) { ss[t] += ss[t + st]; sq[t] += sq[t + st]; }
    __syncthreads();
  }
  if (t < 16) {
    atomicAdd(&stats[t], ss[t]);
    atomicAdd(&stats[16 + t], sq[t]);
  }
}

// a = g*rsqrt(var+eps), s = be - mean*a
__global__ void k_affine(const float* __restrict__ stats, const float* __restrict__ g,
                         const float* __restrict__ be, float invN, float* __restrict__ a,
                         float* __restrict__ s) {
  int c = threadIdx.x;
  if (c < 16) {
    float mean = stats[c] * invN;
    float var = stats[16 + c] * invN - mean * mean;
    float av = g[c] * rsqrtf(var + EPSV);
    a[c] = av;
    s[c] = be[c] - mean * av;
  }
}

// hs_out[row] = (relu(a*in[row]+s) @ W) * dinv[row]   (W: 16x16)
__global__ void k_gemm_small(const float* __restrict__ in, const float* __restrict__ a,
                             const float* __restrict__ s, const float* __restrict__ W,
                             const float* __restrict__ dinv, int N, float* __restrict__ out) {
  int row = blockIdx.x * 256 + threadIdx.x;
  if (row >= N) return;
  const float4* in4 = (const float4*)(in + (size_t)row * 16);
  float v[16];
#pragma unroll
  for (int i = 0; i < 4; i++) {
    float4 tv = in4[i];
    v[i * 4 + 0] = tv.x; v[i * 4 + 1] = tv.y; v[i * 4 + 2] = tv.z; v[i * 4 + 3] = tv.w;
  }
#pragma unroll
  for (int c = 0; c < 16; c++) v[c] = fmaxf(fmaf(a[c], v[c], s[c]), 0.f);
  float acc[16];
#pragma unroll
  for (int c = 0; c < 16; c++) acc[c] = 0.f;
#pragma unroll
  for (int k = 0; k < 16; k++) {
#pragma unroll
    for (int c = 0; c < 16; c++) acc[c] = fmaf(v[k], W[k * 16 + c], acc[c]);
  }
  float dv = dinv[row];
  float4* o4 = (float4*)(out + (size_t)row * 16);
#pragma unroll
  for (int i = 0; i < 4; i++)
    o4[i] = make_float4(acc[i * 4] * dv, acc[i * 4 + 1] * dv, acc[i * 4 + 2] * dv,
                        acc[i * 4 + 3] * dv);
}

// ---------------- launch ----------------

extern "C" void kernel_launch(void* const* d_in, const int* in_sizes, int n_in,
                              void* d_out, int out_size, void* d_ws, size_t ws_size,
                              hipStream_t stream) {
  const float* x = (const float*)d_in[0];
  const int* eidx = (const int*)d_in[1];   // harness passes integers as int32
  const float* W1 = (const float*)d_in[2];
  const float* b1 = (const float*)d_in[3];
  const float* g1 = (const float*)d_in[4];
  const float* be1 = (const float*)d_in[5];
  const float* W2 = (const float*)d_in[6];
  const float* b2 = (const float*)d_in[7];
  const float* g2 = (const float*)d_in[8];
  const float* be2 = (const float*)d_in[9];
  const float* W3 = (const float*)d_in[10];
  const float* b3 = (const float*)d_in[11];
  float* out = (float*)d_out;

  int N = in_sizes[0] / 256;
  int E = in_sizes[1] / 2;
  int NB = (N + BK - 1) / BK;  // dst buckets (<=256 for N<=262144)

  // workspace layout (~26 MB for N=200000, E=3200000)
  char* w = (char*)d_ws;
  float* hs = (float*)w;                                   // N*16 floats = 12.8 MB
  int* csr = (int*)(w + (size_t)N * 16 * 4);               // E ints     = 12.8 MB
  char* p = w + (size_t)N * 16 * 4 + (size_t)E * 4;
  int* offs = (int*)p;                                     // (N+4) ints
  p += (size_t)(N + 4) * 4;
  float* dinv = (float*)p;                                 // N floats
  p += (size_t)N * 4;
  float* stats1 = (float*)p;                               // 32
  float* stats2 = stats1 + 32;                             // 32
  float* a1 = stats2 + 32;
  float* s1 = a1 + 16;
  float* a2 = s1 + 16;
  float* s2 = a2 + 16;
  int* bcnt = (int*)(s2 + 16);                             // 256
  int* bbeg = bcnt + 256;                                  // 257 (pad 260)
  int* ticket = bbeg + 260;                                // 256

  unsigned* staged = (unsigned*)hs;  // staging aliases hs (E*4 == N*16*4 here;
                                     // hs is first written after k_place)

  int gN = (N + 255) / 256;
  int gQ = (N * 4 + 255) / 256;
  int gB = (E + P1CHUNK - 1) / P1CHUNK;

  k_zero<<<1, 256, 0, stream>>>(bcnt, stats1);  // zeros bcnt + stats1/stats2
  k_bcount<<<gB, 256, 0, stream>>>(eidx, E, NB, bcnt);
  k_bscan<<<1, 256, 0, stream>>>(bcnt, NB, E, N, ticket, bbeg, offs);
  k_bin<<<gB, 256, 0, stream>>>(eidx, E, NB, ticket, staged);
  k_place<<<NB, 256, 0, stream>>>(staged, bbeg, N, csr, offs, dinv);

  float* o = out;  // use d_out as the BN-input ping buffer
  float invN = 1.f / (float)N;

  k_gemm1<<<gN, 256, 0, stream>>>(x, W1, dinv, N, hs);
  k_agg<<<gQ, 256, 0, stream>>>(hs, csr, offs, dinv, b1, N, o);
  k_bnstats<<<256, 256, 0, stream>>>(o, N, stats1);
  k_affine<<<1, 64, 0, stream>>>(stats1, g1, be1, invN, a1, s1);
  k_gemm_small<<<gN, 256, 0, stream>>>(o, a1, s1, W2, dinv, N, hs);
  k_agg<<<gQ, 256, 0, stream>>>(hs, csr, offs, dinv, b2, N, o);
  k_bnstats<<<256, 256, 0, stream>>>(o, N, stats2);
  k_affine<<<1, 64, 0, stream>>>(stats2, g2, be2, invN, a2, s2);
  k_gemm_small<<<gN, 256, 0, stream>>>(o, a2, s2, W3, dinv, N, hs);
  k_agg<<<gQ, 256, 0, stream>>>(hs, csr, offs, dinv, b3, N, out);
}